// Round 8
// baseline (273.524 us; speedup 1.0000x reference)
//
#include <hip/hip_runtime.h>
#include <math.h>

#define B_    16
#define CIN   64
#define COUT  128
#define H_    128
#define W_    128
#define CI2   128            // 2*CIN (x ++ silu(x))
#define KTOT  1152           // 9 taps * CI2

typedef __bf16 bf16x8 __attribute__((ext_vector_type(8)));
typedef float  f32x4  __attribute__((ext_vector_type(4)));

#define XT_BYTES  ((size_t)B_ * H_ * W_ * CI2 * 2)   // 67,108,864
#define WC_BYTES  ((size_t)COUT * KTOT * 2)          // 294,912
#define Z_OFF     (XT_BYTES + WC_BYTES)
#define WS_NEED   (Z_OFF + 4096)

// ---------- prep 1: weights -> Wc[co][k] bf16, k = tap*128 + ci2 ----------
__global__ __launch_bounds__(256) void w_prep(const float* __restrict__ sw,
                                              const float* __restrict__ bw,
                                              __bf16* __restrict__ wc,
                                              float* __restrict__ zp) {
    const int i = blockIdx.x * 256 + threadIdx.x;
    if (blockIdx.x == 0) zp[threadIdx.x] = 0.f;  // zeros page (1 KiB)
    if (i >= COUT * KTOT) return;
    const int co = i / KTOT, k = i - co * KTOT;
    const int tap = k >> 7, ci2 = k & 127;
    float v;
    if (ci2 < CIN) {
        const float* p = sw + ((size_t)(co * CIN + ci2) * 9 + tap) * 4;
        v = p[0] + p[1] + p[2] + p[3];
    } else {
        v = bw[(size_t)(co * CIN + (ci2 - CIN)) * 9 + tap];
    }
    wc[(size_t)co * KTOT + k] = (__bf16)v;
}

// ---------- prep 2: x (NCHW fp32) -> Xt (NHWC bf16, ci2 = x ++ silu(x)) ----------
__global__ __launch_bounds__(256) void xt_prep(const float* __restrict__ x,
                                               __bf16* __restrict__ xt) {
    __shared__ __align__(16) __bf16 tile[64][136];
    const int t  = threadIdx.x;
    const int w0 = blockIdx.x * 64;
    const int h  = blockIdx.y;
    const int b  = blockIdx.z;
    const float* xb = x + ((size_t)(b * CIN) * H_ + h) * W_ + w0;
#pragma unroll
    for (int rep = 0; rep < 16; ++rep) {
        const int idx = rep * 256 + t;
        const int ci = idx >> 6, w = idx & 63;
        const float v = xb[(size_t)ci * H_ * W_ + w];
        tile[w][ci]       = (__bf16)v;
        tile[w][CIN + ci] = (__bf16)(v / (1.f + __expf(-v)));
    }
    __syncthreads();
    __bf16* ob = xt + (((size_t)b * H_ + h) * W_ + w0) * CI2;
#pragma unroll
    for (int rep = 0; rep < 4; ++rep) {
        const int idx = rep * 256 + t;
        const int w = idx >> 4, sl = idx & 15;
        *(bf16x8*)(ob + (size_t)w * CI2 + sl * 8) = *(const bf16x8*)(&tile[w][sl * 8]);
    }
}

// ---------- main: implicit-GEMM MFMA conv, depth-1 SW pipeline ----------
// block: 128 couts x (8h x 16w) positions; 4 waves as 2(m) x 2(n); 3 blocks/CU
__global__ __launch_bounds__(256, 3) void kan_mfma(const __bf16* __restrict__ xt,
                                                   const __bf16* __restrict__ wc,
                                                   const float* __restrict__ zp,
                                                   float* __restrict__ out) {
    __shared__ __align__(16) char xs[2880 * 16];   // 180 pos * 256B = 46080B
    const int t    = threadIdx.x;
    const int lane = t & 63, wave = t >> 6;
    const int wm = wave >> 1, wn = wave & 1;
    const int l15 = lane & 15, lq = lane >> 4;
    const int w0 = blockIdx.x * 16, h0 = blockIdx.y * 8, b = blockIdx.z;

    // ---- stage halo tile once: global_load_lds 16B, pre-swizzled source
    const size_t xbase = (size_t)b * (H_ * W_ * CI2);
#pragma unroll
    for (int i = 0; i < 12; ++i) {
        const int s = i * 256 + t;
        if (s < 2880) {
            const int pos = s >> 4, q = s & 15;
            const int ih = pos / 18, iw = pos - ih * 18;
            const int gh = h0 + ih - 1, gw = w0 + iw - 1;
            const int chunk = q ^ (pos & 15);
            const void* src;
            if (gh >= 0 && gh < H_ && gw >= 0 && gw < W_)
                src = (const void*)(xt + xbase + ((size_t)(gh * W_ + gw)) * CI2 + chunk * 8);
            else
                src = (const void*)zp;
            __builtin_amdgcn_global_load_lds(
                (const __attribute__((address_space(1))) unsigned int*)src,
                (__attribute__((address_space(3))) unsigned int*)(xs + s * 16), 16, 0, 0);
        }
    }

    f32x4 acc[4][4] = {};

    const __bf16* arow[4];
#pragma unroll
    for (int m = 0; m < 4; ++m)
        arow[m] = wc + (size_t)(wm * 64 + m * 16 + l15) * KTOT + lq * 8;

    int pos0[4];
#pragma unroll
    for (int n = 0; n < 4; ++n) pos0[n] = (wn * 4 + n) * 18 + l15;

    // 36 linear steps: s -> tap = s>>2, ks = s&3
#define LOADA_(dst, s)                                                          \
    _Pragma("unroll")                                                           \
    for (int m = 0; m < 4; ++m)                                                 \
        dst[m] = *(const bf16x8*)(arow[m] + ((s) >> 2) * 128 + ((s) & 3) * 32);

#define LOADB_(dst, s)                                                          \
    _Pragma("unroll")                                                           \
    for (int n = 0; n < 4; ++n) {                                               \
        const int pos_ = pos0[n] + (((s) >> 2) / 3) * 18 + (((s) >> 2) % 3);    \
        const int swz_ = (((s) & 3) * 4 + lq) ^ (pos_ & 15);                    \
        dst[n] = *(const bf16x8*)(xs + pos_ * 256 + swz_ * 16);                 \
    }

#define MFMAS_(A, Bf)                                                           \
    _Pragma("unroll")                                                           \
    for (int m = 0; m < 4; ++m)                                                 \
        _Pragma("unroll")                                                       \
        for (int n = 0; n < 4; ++n)                                             \
            acc[m][n] = __builtin_amdgcn_mfma_f32_16x16x32_bf16(A[m], Bf[n],    \
                                                                acc[m][n], 0, 0, 0);

    bf16x8 afA[4], afB[4], bfA[4], bfB[4];
    LOADA_(afA, 0);          // A-frags don't touch LDS: hoist above barrier
    __syncthreads();         // the only barrier
    LOADB_(bfA, 0);

#pragma unroll
    for (int s2 = 0; s2 < 36; s2 += 2) {
        if (s2 + 1 < 36) { LOADA_(afB, s2 + 1); LOADB_(bfB, s2 + 1); }
        MFMAS_(afA, bfA);
        if (s2 + 2 < 36) { LOADA_(afA, s2 + 2); LOADB_(bfA, s2 + 2); }
        MFMAS_(afB, bfB);
    }

    // ---- epilogue: D row = co (lq*4+r), col = position (l15); plain stores
    float* ob = out + (size_t)b * COUT * H_ * W_;
#pragma unroll
    for (int m = 0; m < 4; ++m) {
        const int co = wm * 64 + m * 16 + lq * 4;
#pragma unroll
        for (int n = 0; n < 4; ++n) {
            const int ph = wn * 4 + n;
            float* p = ob + ((size_t)co * H_ + (h0 + ph)) * W_ + (w0 + l15);
#pragma unroll
            for (int r = 0; r < 4; ++r)
                p[(size_t)r * H_ * W_] = acc[m][n][r];
        }
    }
#undef LOADA_
#undef LOADB_
#undef MFMAS_
}

// ---------- fallback (round-0 fp32 path, used only if ws too small) ----------
#define TS   16
#define COB  8
#define TIN  18
__global__ __launch_bounds__(256) void spline_sum_kernel(const float* __restrict__ sw,
                                                         float* __restrict__ wsum) {
    int i = blockIdx.x * 256 + threadIdx.x;
    if (i < COUT * CIN * 9) {
        const float4 v = *reinterpret_cast<const float4*>(sw + (size_t)i * 4);
        wsum[i] = v.x + v.y + v.z + v.w;
    }
}
__global__ __launch_bounds__(256) void kan_conv(const float* __restrict__ x,
                                                const float* __restrict__ wsp,
                                                const float* __restrict__ wb,
                                                float* __restrict__ out) {
    __shared__ float xsm[TIN][20];
    __shared__ float ssm[TIN][20];
    const int t = threadIdx.x, tx = t & 15, ty = t >> 4;
    const int w0 = (blockIdx.x & 7) * TS, h0 = (blockIdx.x >> 3) * TS;
    const int co0 = blockIdx.y * COB, b = blockIdx.z;
    float acc[COB];
#pragma unroll
    for (int i = 0; i < COB; ++i) acc[i] = 0.f;
    const float* xb = x + (size_t)b * CIN * H_ * W_;
    for (int ci = 0; ci < CIN; ++ci) {
        __syncthreads();
        const float* xc = xb + (size_t)ci * H_ * W_;
        for (int p = t; p < TIN * TIN; p += 256) {
            int r = p / TIN, c = p - r * TIN;
            int ih = h0 + r - 1, iw = w0 + c - 1;
            float v = 0.f;
            if (ih >= 0 && ih < H_ && iw >= 0 && iw < W_) v = xc[ih * W_ + iw];
            xsm[r][c] = v;
            ssm[r][c] = v / (1.f + expf(-v));
        }
        __syncthreads();
        float xv[9], sv[9];
#pragma unroll
        for (int kh = 0; kh < 3; ++kh)
#pragma unroll
            for (int kw = 0; kw < 3; ++kw) {
                xv[kh * 3 + kw] = xsm[ty + kh][tx + kw];
                sv[kh * 3 + kw] = ssm[ty + kh][tx + kw];
            }
#pragma unroll
        for (int co = 0; co < COB; ++co) {
            const float* w1 = wsp + ((size_t)(co0 + co) * CIN + ci) * 9;
            const float* w2 = wb  + ((size_t)(co0 + co) * CIN + ci) * 9;
#pragma unroll
            for (int k = 0; k < 9; ++k)
                acc[co] += xv[k] * w1[k] + sv[k] * w2[k];
        }
    }
    const int oh = h0 + ty, ow = w0 + tx;
#pragma unroll
    for (int co = 0; co < COB; ++co)
        out[(((size_t)b * COUT + (co0 + co)) * H_ + oh) * W_ + ow] = acc[co];
}

extern "C" void kernel_launch(void* const* d_in, const int* in_sizes, int n_in,
                              void* d_out, int out_size, void* d_ws, size_t ws_size,
                              hipStream_t stream) {
    const float* x  = (const float*)d_in[0];
    const float* sw = (const float*)d_in[1];   // (COUT,CIN,3,3,4)
    const float* bw = (const float*)d_in[2];   // (COUT,CIN,3,3)
    float* out = (float*)d_out;

    if (ws_size >= WS_NEED) {
        __bf16* xt = (__bf16*)d_ws;
        __bf16* wc = (__bf16*)((char*)d_ws + XT_BYTES);
        float*  zp = (float*)((char*)d_ws + Z_OFF);
        w_prep<<<(COUT * KTOT + 255) / 256, 256, 0, stream>>>(sw, bw, wc, zp);
        xt_prep<<<dim3(2, H_, B_), 256, 0, stream>>>(x, xt);
        kan_mfma<<<dim3(W_ / 16, H_ / 8, B_), 256, 0, stream>>>(xt, wc, zp, out);
    } else {
        float* wsum = (float*)d_ws;
        spline_sum_kernel<<<(COUT * CIN * 9 + 255) / 256, 256, 0, stream>>>(sw, wsum);
        kan_conv<<<dim3(64, COUT / COB, B_), 256, 0, stream>>>(x, wsum, bw, out);
    }
}

// Round 10
// 187.188 us; speedup vs baseline: 1.4612x; 1.4612x over previous
//
#include <hip/hip_runtime.h>
#include <math.h>

#define B_    16
#define CIN   64
#define COUT  128
#define H_    128
#define W_    128
#define CI2   128            // 2*CIN (x ++ silu(x))
#define KTOT  1152           // 9 taps * CI2

typedef __bf16 bf16x8 __attribute__((ext_vector_type(8)));
typedef float  f32x4  __attribute__((ext_vector_type(4)));

#define XT_BYTES  ((size_t)B_ * H_ * W_ * CI2 * 2)   // 67,108,864
#define WC_BYTES  ((size_t)COUT * KTOT * 2)          // 294,912
#define Z_OFF     (XT_BYTES + WC_BYTES)
#define WS_NEED   (Z_OFF + 4096)

// ---------- prep 1: weights -> Wc in WAVE-FRAGMENT order ----------
// main-kernel lane (l15,lq), wave-half wm, frag m, step s=tap*4+ks reads
// 8 elems at offset ((((wm*4+m)*36 + s)*64) + lq*16 + l15)*8  -> one
// contiguous 1KB chunk per (wm,m,s) = fully coalesced wave load.
__global__ __launch_bounds__(256) void w_prep(const float* __restrict__ sw,
                                              const float* __restrict__ bw,
                                              __bf16* __restrict__ wc,
                                              float* __restrict__ zp) {
    const int i = blockIdx.x * 256 + threadIdx.x;
    if (blockIdx.x == 0) zp[threadIdx.x] = 0.f;  // zeros page (1 KiB)
    if (i >= COUT * KTOT) return;
    const int co = i / KTOT, k = i - co * KTOT;
    const int tap = k >> 7, ci2 = k & 127;
    float v;
    if (ci2 < CIN) {
        const float* p = sw + ((size_t)(co * CIN + ci2) * 9 + tap) * 4;
        v = p[0] + p[1] + p[2] + p[3];
    } else {
        v = bw[(size_t)(co * CIN + (ci2 - CIN)) * 9 + tap];
    }
    // permuted fragment-order offset
    const int wm = co >> 6, m = (co >> 4) & 3, l15 = co & 15;
    const int ks = (k >> 5) & 3, lq = (k >> 3) & 3, e = k & 7;
    const size_t off =
        ((size_t)(((wm * 4 + m) * 9 + tap) * 4 + ks) * 64 + lq * 16 + l15) * 8 + e;
    wc[off] = (__bf16)v;
}

// ---------- prep 2: x (NCHW fp32) -> Xt (NHWC bf16, ci2 = x ++ silu(x)) ----------
__global__ __launch_bounds__(256) void xt_prep(const float* __restrict__ x,
                                               __bf16* __restrict__ xt) {
    __shared__ __align__(16) __bf16 tile[64][136];
    const int t  = threadIdx.x;
    const int w0 = blockIdx.x * 64;
    const int h  = blockIdx.y;
    const int b  = blockIdx.z;
    const float* xb = x + ((size_t)(b * CIN) * H_ + h) * W_ + w0;
#pragma unroll
    for (int rep = 0; rep < 16; ++rep) {
        const int idx = rep * 256 + t;
        const int ci = idx >> 6, w = idx & 63;
        const float v = xb[(size_t)ci * H_ * W_ + w];
        tile[w][ci]       = (__bf16)v;
        tile[w][CIN + ci] = (__bf16)(v / (1.f + __expf(-v)));
    }
    __syncthreads();
    __bf16* ob = xt + (((size_t)b * H_ + h) * W_ + w0) * CI2;
#pragma unroll
    for (int rep = 0; rep < 4; ++rep) {
        const int idx = rep * 256 + t;
        const int w = idx >> 4, sl = idx & 15;
        *(bf16x8*)(ob + (size_t)w * CI2 + sl * 8) = *(const bf16x8*)(&tile[w][sl * 8]);
    }
}

// ---------- main: implicit-GEMM MFMA conv, depth-1 SW pipeline ----------
// block: 128 couts x (8h x 16w) positions; 4 waves as 2(m) x 2(n); 2 blocks/CU
__global__ __launch_bounds__(256, 2) void kan_mfma(const __bf16* __restrict__ xt,
                                                   const __bf16* __restrict__ wc,
                                                   const float* __restrict__ zp,
                                                   float* __restrict__ out) {
    __shared__ __align__(16) char xs[2880 * 16];   // 180 pos * 256B = 46080B
    const int t    = threadIdx.x;
    const int lane = t & 63, wave = t >> 6;
    const int wm = wave >> 1, wn = wave & 1;
    const int l15 = lane & 15, lq = lane >> 4;
    const int w0 = blockIdx.x * 16, h0 = blockIdx.y * 8, b = blockIdx.z;

    // ---- stage halo tile once: global_load_lds 16B, pre-swizzled source
    const size_t xbase = (size_t)b * (H_ * W_ * CI2);
#pragma unroll
    for (int i = 0; i < 12; ++i) {
        const int s = i * 256 + t;
        if (s < 2880) {
            const int pos = s >> 4, q = s & 15;
            const int ih = pos / 18, iw = pos - ih * 18;
            const int gh = h0 + ih - 1, gw = w0 + iw - 1;
            const int chunk = q ^ (pos & 15);
            const void* src;
            if (gh >= 0 && gh < H_ && gw >= 0 && gw < W_)
                src = (const void*)(xt + xbase + ((size_t)(gh * W_ + gw)) * CI2 + chunk * 8);
            else
                src = (const void*)zp;
            __builtin_amdgcn_global_load_lds(
                (const __attribute__((address_space(1))) unsigned int*)src,
                (__attribute__((address_space(3))) unsigned int*)(xs + s * 16), 16, 0, 0);
        }
    }

    f32x4 acc[4][4] = {};

    // A-fragment base pointers (permuted layout): step s adds s*512 elems
    const __bf16* arow[4];
#pragma unroll
    for (int m = 0; m < 4; ++m)
        arow[m] = wc + ((size_t)(wm * 4 + m) * 36 * 64 + lq * 16 + l15) * 8;

    int pos0[4];
#pragma unroll
    for (int n = 0; n < 4; ++n) pos0[n] = (wn * 4 + n) * 18 + l15;

    // 36 linear steps: s -> tap = s>>2, ks = s&3
#define LOADA_(dst, s)                                                          \
    _Pragma("unroll")                                                           \
    for (int m = 0; m < 4; ++m)                                                 \
        dst[m] = *(const bf16x8*)(arow[m] + (size_t)(s) * 512);

#define LOADB_(dst, s)                                                          \
    _Pragma("unroll")                                                           \
    for (int n = 0; n < 4; ++n) {                                               \
        const int pos_ = pos0[n] + (((s) >> 2) / 3) * 18 + (((s) >> 2) % 3);    \
        const int swz_ = (((s) & 3) * 4 + lq) ^ (pos_ & 15);                    \
        dst[n] = *(const bf16x8*)(xs + pos_ * 256 + swz_ * 16);                 \
    }

#define MFMAS_(A, Bf)                                                           \
    _Pragma("unroll")                                                           \
    for (int m = 0; m < 4; ++m)                                                 \
        _Pragma("unroll")                                                       \
        for (int n = 0; n < 4; ++n)                                             \
            acc[m][n] = __builtin_amdgcn_mfma_f32_16x16x32_bf16(A[m], Bf[n],    \
                                                                acc[m][n], 0, 0, 0);

    bf16x8 afA[4], afB[4], bfA[4], bfB[4];
    LOADA_(afA, 0);          // A-frags don't touch LDS: hoist above barrier
    __syncthreads();         // the only barrier
    LOADB_(bfA, 0);

#pragma unroll
    for (int s2 = 0; s2 < 36; s2 += 2) {
        if (s2 + 1 < 36) { LOADA_(afB, s2 + 1); LOADB_(bfB, s2 + 1); }
        MFMAS_(afA, bfA);
        if (s2 + 2 < 36) { LOADA_(afA, s2 + 2); LOADB_(bfA, s2 + 2); }
        MFMAS_(afB, bfB);
    }

    // ---- epilogue: D row = co (lq*4+r), col = position (l15); plain stores
    float* ob = out + (size_t)b * COUT * H_ * W_;
#pragma unroll
    for (int m = 0; m < 4; ++m) {
        const int co = wm * 64 + m * 16 + lq * 4;
#pragma unroll
        for (int n = 0; n < 4; ++n) {
            const int ph = wn * 4 + n;
            float* p = ob + ((size_t)co * H_ + (h0 + ph)) * W_ + (w0 + l15);
#pragma unroll
            for (int r = 0; r < 4; ++r)
                p[(size_t)r * H_ * W_] = acc[m][n][r];
        }
    }
#undef LOADA_
#undef LOADB_
#undef MFMAS_
}

// ---------- fallback (round-0 fp32 path, used only if ws too small) ----------
#define TS   16
#define COB  8
#define TIN  18
__global__ __launch_bounds__(256) void spline_sum_kernel(const float* __restrict__ sw,
                                                         float* __restrict__ wsum) {
    int i = blockIdx.x * 256 + threadIdx.x;
    if (i < COUT * CIN * 9) {
        const float4 v = *reinterpret_cast<const float4*>(sw + (size_t)i * 4);
        wsum[i] = v.x + v.y + v.z + v.w;
    }
}
__global__ __launch_bounds__(256) void kan_conv(const float* __restrict__ x,
                                                const float* __restrict__ wsp,
                                                const float* __restrict__ wb,
                                                float* __restrict__ out) {
    __shared__ float xsm[TIN][20];
    __shared__ float ssm[TIN][20];
    const int t = threadIdx.x, tx = t & 15, ty = t >> 4;
    const int w0 = (blockIdx.x & 7) * TS, h0 = (blockIdx.x >> 3) * TS;
    const int co0 = blockIdx.y * COB, b = blockIdx.z;
    float acc[COB];
#pragma unroll
    for (int i = 0; i < COB; ++i) acc[i] = 0.f;
    const float* xb = x + (size_t)b * CIN * H_ * W_;
    for (int ci = 0; ci < CIN; ++ci) {
        __syncthreads();
        const float* xc = xb + (size_t)ci * H_ * W_;
        for (int p = t; p < TIN * TIN; p += 256) {
            int r = p / TIN, c = p - r * TIN;
            int ih = h0 + r - 1, iw = w0 + c - 1;
            float v = 0.f;
            if (ih >= 0 && ih < H_ && iw >= 0 && iw < W_) v = xc[ih * W_ + iw];
            xsm[r][c] = v;
            ssm[r][c] = v / (1.f + expf(-v));
        }
        __syncthreads();
        float xv[9], sv[9];
#pragma unroll
        for (int kh = 0; kh < 3; ++kh)
#pragma unroll
            for (int kw = 0; kw < 3; ++kw) {
                xv[kh * 3 + kw] = xsm[ty + kh][tx + kw];
                sv[kh * 3 + kw] = ssm[ty + kh][tx + kw];
            }
#pragma unroll
        for (int co = 0; co < COB; ++co) {
            const float* w1 = wsp + ((size_t)(co0 + co) * CIN + ci) * 9;
            const float* w2 = wb  + ((size_t)(co0 + co) * CIN + ci) * 9;
#pragma unroll
            for (int k = 0; k < 9; ++k)
                acc[co] += xv[k] * w1[k] + sv[k] * w2[k];
        }
    }
    const int oh = h0 + ty, ow = w0 + tx;
#pragma unroll
    for (int co = 0; co < COB; ++co)
        out[(((size_t)b * COUT + (co0 + co)) * H_ + oh) * W_ + ow] = acc[co];
}

extern "C" void kernel_launch(void* const* d_in, const int* in_sizes, int n_in,
                              void* d_out, int out_size, void* d_ws, size_t ws_size,
                              hipStream_t stream) {
    const float* x  = (const float*)d_in[0];
    const float* sw = (const float*)d_in[1];   // (COUT,CIN,3,3,4)
    const float* bw = (const float*)d_in[2];   // (COUT,CIN,3,3)
    float* out = (float*)d_out;

    if (ws_size >= WS_NEED) {
        __bf16* xt = (__bf16*)d_ws;
        __bf16* wc = (__bf16*)((char*)d_ws + XT_BYTES);
        float*  zp = (float*)((char*)d_ws + Z_OFF);
        w_prep<<<(COUT * KTOT + 255) / 256, 256, 0, stream>>>(sw, bw, wc, zp);
        xt_prep<<<dim3(2, H_, B_), 256, 0, stream>>>(x, xt);
        kan_mfma<<<dim3(W_ / 16, H_ / 8, B_), 256, 0, stream>>>(xt, wc, zp, out);
    } else {
        float* wsum = (float*)d_ws;
        spline_sum_kernel<<<(COUT * CIN * 9 + 255) / 256, 256, 0, stream>>>(sw, wsum);
        kan_conv<<<dim3(64, COUT / COB, B_), 256, 0, stream>>>(x, wsum, bw, out);
    }
}

// Round 11
// 185.355 us; speedup vs baseline: 1.4757x; 1.0099x over previous
//
#include <hip/hip_runtime.h>
#include <math.h>

#define B_    16
#define CIN   64
#define COUT  128
#define H_    128
#define W_    128
#define CI2   128            // 2*CIN (x ++ silu(x))
#define KTOT  1152           // 9 taps * CI2

typedef __bf16 bf16x8 __attribute__((ext_vector_type(8)));
typedef float  f32x4  __attribute__((ext_vector_type(4)));

#define XT_BYTES  ((size_t)B_ * H_ * W_ * CI2 * 2)   // 67,108,864
#define WC_BYTES  ((size_t)COUT * KTOT * 2)          // 294,912
#define Z_OFF     (XT_BYTES + WC_BYTES)
#define WS_NEED   (Z_OFF + 4096)

// ---------- prep 1: weights -> Wc in WAVE-FRAGMENT order ----------
__global__ __launch_bounds__(256) void w_prep(const float* __restrict__ sw,
                                              const float* __restrict__ bw,
                                              __bf16* __restrict__ wc,
                                              float* __restrict__ zp) {
    const int i = blockIdx.x * 256 + threadIdx.x;
    if (blockIdx.x == 0) zp[threadIdx.x] = 0.f;  // zeros page (1 KiB)
    if (i >= COUT * KTOT) return;
    const int co = i / KTOT, k = i - co * KTOT;
    const int tap = k >> 7, ci2 = k & 127;
    float v;
    if (ci2 < CIN) {
        const float* p = sw + ((size_t)(co * CIN + ci2) * 9 + tap) * 4;
        v = p[0] + p[1] + p[2] + p[3];
    } else {
        v = bw[(size_t)(co * CIN + (ci2 - CIN)) * 9 + tap];
    }
    // permuted fragment-order offset
    const int wm = co >> 6, m = (co >> 4) & 3, l15 = co & 15;
    const int ks = (k >> 5) & 3, lq = (k >> 3) & 3, e = k & 7;
    const size_t off =
        ((size_t)(((wm * 4 + m) * 9 + tap) * 4 + ks) * 64 + lq * 16 + l15) * 8 + e;
    wc[off] = (__bf16)v;
}

// ---------- prep 2: x (NCHW fp32) -> Xt (NHWC bf16, ci2 = x ++ silu(x)) ----------
__global__ __launch_bounds__(256) void xt_prep(const float* __restrict__ x,
                                               __bf16* __restrict__ xt) {
    __shared__ __align__(16) __bf16 tile[64][136];
    const int t  = threadIdx.x;
    const int w0 = blockIdx.x * 64;
    const int h  = blockIdx.y;
    const int b  = blockIdx.z;
    const float* xb = x + ((size_t)(b * CIN) * H_ + h) * W_ + w0;
#pragma unroll
    for (int rep = 0; rep < 16; ++rep) {
        const int idx = rep * 256 + t;
        const int ci = idx >> 6, w = idx & 63;
        const float v = xb[(size_t)ci * H_ * W_ + w];
        tile[w][ci]       = (__bf16)v;
        tile[w][CIN + ci] = (__bf16)(v / (1.f + __expf(-v)));
    }
    __syncthreads();
    __bf16* ob = xt + (((size_t)b * H_ + h) * W_ + w0) * CI2;
#pragma unroll
    for (int rep = 0; rep < 4; ++rep) {
        const int idx = rep * 256 + t;
        const int w = idx >> 4, sl = idx & 15;
        *(bf16x8*)(ob + (size_t)w * CI2 + sl * 8) = *(const bf16x8*)(&tile[w][sl * 8]);
    }
}

// ---------- main: implicit-GEMM MFMA conv ----------
// 1-D grid 2048, XCD-bijective swizzle: each XCD gets a contiguous 256-work
// chunk (= 2 whole images) -> neighbor tiles share L2 (write-merge + halo hits)
__global__ __launch_bounds__(256, 2) void kan_mfma(const __bf16* __restrict__ xt,
                                                   const __bf16* __restrict__ wc,
                                                   const float* __restrict__ zp,
                                                   float* __restrict__ out) {
    __shared__ __align__(16) char xs[2880 * 16];   // 180 pos * 256B = 46080B
    const int t    = threadIdx.x;
    const int lane = t & 63, wave = t >> 6;
    const int wm = wave >> 1, wn = wave & 1;
    const int l15 = lane & 15, lq = lane >> 4;

    // XCD swizzle: orig%8 = XCD; give XCD k works [k*256, (k+1)*256)
    const int orig = blockIdx.x;                     // 0..2047
    const int wid  = (orig & 7) * 256 + (orig >> 3); // bijective (2048%8==0)
    const int b  = wid >> 7;
    const int hy = (wid & 127) >> 3, wx = wid & 7;
    const int w0 = wx * 16, h0 = hy * 8;

    // ---- stage halo tile once: global_load_lds 16B, pre-swizzled source
    const size_t xbase = (size_t)b * (H_ * W_ * CI2);
#pragma unroll
    for (int i = 0; i < 12; ++i) {
        const int s = i * 256 + t;
        if (s < 2880) {
            const int pos = s >> 4, q = s & 15;
            const int ih = pos / 18, iw = pos - ih * 18;
            const int gh = h0 + ih - 1, gw = w0 + iw - 1;
            const int chunk = q ^ (pos & 15);
            const void* src;
            if (gh >= 0 && gh < H_ && gw >= 0 && gw < W_)
                src = (const void*)(xt + xbase + ((size_t)(gh * W_ + gw)) * CI2 + chunk * 8);
            else
                src = (const void*)zp;
            __builtin_amdgcn_global_load_lds(
                (const __attribute__((address_space(1))) unsigned int*)src,
                (__attribute__((address_space(3))) unsigned int*)(xs + s * 16), 16, 0, 0);
        }
    }

    f32x4 acc[4][4] = {};

    // A-fragment base pointers (permuted layout): step s adds s*512 elems
    const __bf16* arow[4];
#pragma unroll
    for (int m = 0; m < 4; ++m)
        arow[m] = wc + ((size_t)(wm * 4 + m) * 36 * 64 + lq * 16 + l15) * 8;

    int pos0[4];
#pragma unroll
    for (int n = 0; n < 4; ++n) pos0[n] = (wn * 4 + n) * 18 + l15;

    // 36 linear steps: s -> tap = s>>2, ks = s&3 (guarded; s is unroll-const)
#define LOADA_(dst, s)                                                          \
    if ((s) < 36) {                                                             \
        _Pragma("unroll")                                                       \
        for (int m = 0; m < 4; ++m)                                             \
            dst[m] = *(const bf16x8*)(arow[m] + (size_t)(s) * 512);             \
    }

#define LOADB_(dst, s)                                                          \
    if ((s) < 36) {                                                             \
        _Pragma("unroll")                                                       \
        for (int n = 0; n < 4; ++n) {                                           \
            const int pos_ = pos0[n] + (((s) >> 2) / 3) * 18 + (((s) >> 2) % 3);\
            const int swz_ = (((s) & 3) * 4 + lq) ^ (pos_ & 15);                \
            dst[n] = *(const bf16x8*)(xs + pos_ * 256 + swz_ * 16);             \
        }                                                                       \
    }

#define MFMAS_(A, Bf)                                                           \
    _Pragma("unroll")                                                           \
    for (int m = 0; m < 4; ++m)                                                 \
        _Pragma("unroll")                                                       \
        for (int n = 0; n < 4; ++n)                                             \
            acc[m][n] = __builtin_amdgcn_mfma_f32_16x16x32_bf16(A[m], Bf[n],    \
                                                                acc[m][n], 0, 0, 0);

    bf16x8 a0[4], a1[4], a2[4], b0[4], b1[4];
    LOADA_(a0, 0);           // A-frags don't touch LDS: hoist above barrier
    LOADA_(a1, 1);
    __syncthreads();         // the only barrier
    LOADB_(b0, 0);

    // depth-2 A / depth-1 B prefetch; 6-step period (3 A-bufs x 2 B-bufs)
#pragma unroll
    for (int u = 0; u < 36; u += 6) {
        LOADA_(a2, u + 2); LOADB_(b1, u + 1); MFMAS_(a0, b0);
        LOADA_(a0, u + 3); LOADB_(b0, u + 2); MFMAS_(a1, b1);
        LOADA_(a1, u + 4); LOADB_(b1, u + 3); MFMAS_(a2, b0);
        LOADA_(a2, u + 5); LOADB_(b0, u + 4); MFMAS_(a0, b1);
        LOADA_(a0, u + 6); LOADB_(b1, u + 5); MFMAS_(a1, b0);
        LOADA_(a1, u + 7); LOADB_(b0, u + 6); MFMAS_(a2, b1);
    }

    // ---- epilogue: D row = co (lq*4+r), col = position (l15); plain stores
    float* ob = out + (size_t)b * COUT * H_ * W_;
#pragma unroll
    for (int m = 0; m < 4; ++m) {
        const int co = wm * 64 + m * 16 + lq * 4;
#pragma unroll
        for (int n = 0; n < 4; ++n) {
            const int ph = wn * 4 + n;
            float* p = ob + ((size_t)co * H_ + (h0 + ph)) * W_ + (w0 + l15);
#pragma unroll
            for (int r = 0; r < 4; ++r)
                p[(size_t)r * H_ * W_] = acc[m][n][r];
        }
    }
#undef LOADA_
#undef LOADB_
#undef MFMAS_
}

// ---------- fallback (round-0 fp32 path, used only if ws too small) ----------
#define TS   16
#define COB  8
#define TIN  18
__global__ __launch_bounds__(256) void spline_sum_kernel(const float* __restrict__ sw,
                                                         float* __restrict__ wsum) {
    int i = blockIdx.x * 256 + threadIdx.x;
    if (i < COUT * CIN * 9) {
        const float4 v = *reinterpret_cast<const float4*>(sw + (size_t)i * 4);
        wsum[i] = v.x + v.y + v.z + v.w;
    }
}
__global__ __launch_bounds__(256) void kan_conv(const float* __restrict__ x,
                                                const float* __restrict__ wsp,
                                                const float* __restrict__ wb,
                                                float* __restrict__ out) {
    __shared__ float xsm[TIN][20];
    __shared__ float ssm[TIN][20];
    const int t = threadIdx.x, tx = t & 15, ty = t >> 4;
    const int w0 = (blockIdx.x & 7) * TS, h0 = (blockIdx.x >> 3) * TS;
    const int co0 = blockIdx.y * COB, b = blockIdx.z;
    float acc[COB];
#pragma unroll
    for (int i = 0; i < COB; ++i) acc[i] = 0.f;
    const float* xb = x + (size_t)b * CIN * H_ * W_;
    for (int ci = 0; ci < CIN; ++ci) {
        __syncthreads();
        const float* xc = xb + (size_t)ci * H_ * W_;
        for (int p = t; p < TIN * TIN; p += 256) {
            int r = p / TIN, c = p - r * TIN;
            int ih = h0 + r - 1, iw = w0 + c - 1;
            float v = 0.f;
            if (ih >= 0 && ih < H_ && iw >= 0 && iw < W_) v = xc[ih * W_ + iw];
            xsm[r][c] = v;
            ssm[r][c] = v / (1.f + expf(-v));
        }
        __syncthreads();
        float xv[9], sv[9];
#pragma unroll
        for (int kh = 0; kh < 3; ++kh)
#pragma unroll
            for (int kw = 0; kw < 3; ++kw) {
                xv[kh * 3 + kw] = xsm[ty + kh][tx + kw];
                sv[kh * 3 + kw] = ssm[ty + kh][tx + kw];
            }
#pragma unroll
        for (int co = 0; co < COB; ++co) {
            const float* w1 = wsp + ((size_t)(co0 + co) * CIN + ci) * 9;
            const float* w2 = wb  + ((size_t)(co0 + co) * CIN + ci) * 9;
#pragma unroll
            for (int k = 0; k < 9; ++k)
                acc[co] += xv[k] * w1[k] + sv[k] * w2[k];
        }
    }
    const int oh = h0 + ty, ow = w0 + tx;
#pragma unroll
    for (int co = 0; co < COB; ++co)
        out[(((size_t)b * COUT + (co0 + co)) * H_ + oh) * W_ + ow] = acc[co];
}

extern "C" void kernel_launch(void* const* d_in, const int* in_sizes, int n_in,
                              void* d_out, int out_size, void* d_ws, size_t ws_size,
                              hipStream_t stream) {
    const float* x  = (const float*)d_in[0];
    const float* sw = (const float*)d_in[1];   // (COUT,CIN,3,3,4)
    const float* bw = (const float*)d_in[2];   // (COUT,CIN,3,3)
    float* out = (float*)d_out;

    if (ws_size >= WS_NEED) {
        __bf16* xt = (__bf16*)d_ws;
        __bf16* wc = (__bf16*)((char*)d_ws + XT_BYTES);
        float*  zp = (float*)((char*)d_ws + Z_OFF);
        w_prep<<<(COUT * KTOT + 255) / 256, 256, 0, stream>>>(sw, bw, wc, zp);
        xt_prep<<<dim3(2, H_, B_), 256, 0, stream>>>(x, xt);
        kan_mfma<<<dim3((W_ / 16) * (H_ / 8) * B_), 256, 0, stream>>>(xt, wc, zp, out);
    } else {
        float* wsum = (float*)d_ws;
        spline_sum_kernel<<<(COUT * CIN * 9 + 255) / 256, 256, 0, stream>>>(sw, wsum);
        kan_conv<<<dim3(64, COUT / COB, B_), 256, 0, stream>>>(x, wsum, bw, out);
    }
}